// Round 5
// baseline (557.193 us; speedup 1.0000x reference)
//
#include <hip/hip_runtime.h>

// ---------------------------------------------------------------------------
// 2-layer hetero GraphSAGE, bf16-MFMA.
// R5: - Song-side GEMM+aggregation FUSED (MFMA result staged in LDS; no Gs
//       round-trip). Aggregation uses quad-group (16 lanes x 16B per row) +
//       predicated 8-rounds => all loads in a round independent (deg~5 was
//       a serialized latency chain before).
//     - Playlist-side standalone agg gets the same quad-group structure.
//     - CSR build stays XCD-chunked (R4); P-GEMMs stay B-resident (R3).
// ---------------------------------------------------------------------------

typedef __attribute__((ext_vector_type(8))) short bfrag;   // 8 bf16 (4 VGPRs)
typedef __attribute__((ext_vector_type(4))) float ffrag;   // 4 fp32 acc
typedef unsigned short u16;
typedef unsigned int u32;

static inline size_t ws_align(size_t x) { return (x + 255) & ~size_t(255); }

__device__ inline u16 f2bf(float f) {
  union { float f; u32 u; } v; v.f = f;
  u32 r = v.u + 0x7fffu + ((v.u >> 16) & 1u);   // round-nearest-even
  return (u16)(r >> 16);
}
__device__ inline u32 pack2(float a, float b) {
  return (u32)f2bf(a) | ((u32)f2bf(b) << 16);
}
__device__ inline float bf_lo(u32 p) {
  union { u32 u; float f; } v; v.u = p << 16; return v.f;
}
__device__ inline float bf_hi(u32 p) {
  union { u32 u; float f; } v; v.u = p & 0xffff0000u; return v.f;
}

// ---- fused prep: zero counters, conv weights, conv songs, gather playlists -
__global__ __launch_bounds__(256) void prep_k(
    const float* __restrict__ w0, const float* __restrict__ w1,
    const float* __restrict__ w2, const float* __restrict__ w3,
    const float* __restrict__ w4, const float* __restrict__ w5,
    const float* __restrict__ w6, const float* __restrict__ w7,
    u16* __restrict__ Wt,
    const float* __restrict__ song_x, u16* __restrict__ xs, int ns4,
    const float* __restrict__ emb, const int* __restrict__ pid,
    u16* __restrict__ xp, int np,
    int* __restrict__ zero_region, int nzero)
{
  int g0 = blockIdx.x * 256 + threadIdx.x;
  int gs = gridDim.x * 256;
  for (int i = g0; i < nzero; i += gs) zero_region[i] = 0;
  const float* ws[8] = {w0, w1, w2, w3, w4, w5, w6, w7};
  for (int idx = g0; idx < 8 * 16384; idx += gs) {
    int m = idx >> 14, rem = idx & 16383;
    int n = rem >> 7, k = rem & 127;
    Wt[idx] = f2bf(ws[m][k * 128 + n]);
  }
  for (int i = g0; i < ns4; i += gs) {
    float4 v = ((const float4*)song_x)[i];
    ushort4 o;
    o.x = f2bf(v.x); o.y = f2bf(v.y); o.z = f2bf(v.z); o.w = f2bf(v.w);
    ((ushort4*)xs)[i] = o;
  }
  for (int i = g0; i < np * 32; i += gs) {
    int node = i >> 5, q = i & 31;
    float4 v = ((const float4*)(emb + (size_t)pid[node] * 128))[q];
    ushort4 o;
    o.x = f2bf(v.x); o.y = f2bf(v.y); o.z = f2bf(v.z); o.w = f2bf(v.w);
    ((ushort4*)(xp + (size_t)node * 128))[q] = o;
  }
}

// ---- CSR build (XCD-chunked: chunk id = blockIdx&7) ------------------------
__global__ __launch_bounds__(256) void hist_k(
    const int* __restrict__ es, const int* __restrict__ ep,
    int* __restrict__ cnt_s, int* __restrict__ cnt_p,
    int e, int pch, int sch)
{
  int j = blockIdx.x & 7;
  int g = blockIdx.x >> 3;
  int nb = gridDim.x >> 3;
  int p_lo = j * pch, s_lo = j * sch;
  for (int i = g * 256 + threadIdx.x; i < e; i += nb * 256) {
    int p = ep[i], s = es[i];
    if ((u32)(p - p_lo) < (u32)pch) atomicAdd(&cnt_p[p], 1);
    if ((u32)(s - s_lo) < (u32)sch) atomicAdd(&cnt_s[s], 1);
  }
}

__global__ __launch_bounds__(256) void base2_k(
    const int* __restrict__ cnt_p, int* __restrict__ base_p, int* __restrict__ cur_p,
    const int* __restrict__ cnt_s, int* __restrict__ base_s, int* __restrict__ cur_s,
    int* __restrict__ gcnt, int np, int ns, int nbp)
{
  __shared__ int sh[256];
  __shared__ int bb;
  int t = threadIdx.x;
  const int* cnt; int* base; int* cur; int* gc; int n; int i;
  if ((int)blockIdx.x < nbp) {
    cnt = cnt_p; base = base_p; cur = cur_p; gc = gcnt; n = np;
    i = blockIdx.x * 256 + t;
  } else {
    cnt = cnt_s; base = base_s; cur = cur_s; gc = gcnt + 1; n = ns;
    i = (blockIdx.x - nbp) * 256 + t;
  }
  int v = (i < n) ? cnt[i] : 0;
  sh[t] = v;
  __syncthreads();
  for (int off = 1; off < 256; off <<= 1) {
    int tv = (t >= off) ? sh[t - off] : 0;
    __syncthreads();
    sh[t] += tv;
    __syncthreads();
  }
  if (t == 255) bb = atomicAdd(gc, sh[255]);
  __syncthreads();
  if (i < n) {
    int e = bb + sh[t] - v;
    base[i] = e;
    cur[i] = e;
  }
}

__global__ __launch_bounds__(256) void place_k(
    const int* __restrict__ es, const int* __restrict__ ep,
    int* __restrict__ cur_s, int* __restrict__ cur_p,
    int* __restrict__ csr_s, int* __restrict__ csr_p,
    int e, int pch, int sch)
{
  int j = blockIdx.x & 7;
  int g = blockIdx.x >> 3;
  int nb = gridDim.x >> 3;
  int p_lo = j * pch, s_lo = j * sch;
  for (int i = g * 256 + threadIdx.x; i < e; i += nb * 256) {
    int p = ep[i], s = es[i];
    if ((u32)(p - p_lo) < (u32)pch) csr_p[atomicAdd(&cur_p[p], 1)] = s;
    if ((u32)(s - s_lo) < (u32)sch) csr_s[atomicAdd(&cur_s[s], 1)] = p;
  }
}

// ---- quad-group mean aggregation (no post): out bf16 -----------------------
// Block = 256 thr = 4 waves; wave = 4 groups of 16 lanes; group handles 4 rows
// sequentially, 16 lanes x 16B cover a 256B row. Rounds of 8 predicated loads.
__global__ __launch_bounds__(256) void agg_quad_k(
    const u16* __restrict__ feat, const int* __restrict__ csr,
    const int* __restrict__ base, const int* __restrict__ cnt,
    u16* __restrict__ out, int n)
{
  int lane = threadIdx.x & 63;
  int wave = threadIdx.x >> 6;
  int g = lane >> 4, lr = lane & 15;
  int rowbase = blockIdx.x * 64 + wave * 16 + g * 4;
#pragma unroll 1
  for (int t = 0; t < 4; t++) {
    int gv = rowbase + t;
    bool valid = gv < n;
    int b = 0, c = 0;
    if (valid) { b = base[gv]; c = cnt[gv]; }
    float s0=0,s1=0,s2=0,s3=0,s4=0,s5=0,s6=0,s7=0;
    for (int i = 0; i < c; i += 8) {
      int m = c - i;
      int idx[8];
#pragma unroll
      for (int u = 0; u < 8; u++) idx[u] = csr[b + i + min(u, m - 1)];
#pragma unroll
      for (int u = 0; u < 8; u++) {
        uint4 v = ((const uint4*)(feat + (size_t)idx[u] * 128))[lr];
        if (u < m) {
          s0 += bf_lo(v.x); s1 += bf_hi(v.x);
          s2 += bf_lo(v.y); s3 += bf_hi(v.y);
          s4 += bf_lo(v.z); s5 += bf_hi(v.z);
          s6 += bf_lo(v.w); s7 += bf_hi(v.w);
        }
      }
    }
    if (valid) {
      float inv = (c > 0) ? 1.0f / (float)c : 0.0f;
      uint4 o;
      o.x = pack2(s0 * inv, s1 * inv);
      o.y = pack2(s2 * inv, s3 * inv);
      o.z = pack2(s4 * inv, s5 * inv);
      o.w = pack2(s6 * inv, s7 * inv);
      ((uint4*)(out + (size_t)gv * 128))[lr] = o;
    }
  }
}

// ---- FUSED song-side: out = act( mean(feat[csr]) + A@Wt + bias ) -----------
// Phase 1: B-resident MFMA (R3 layout) -> LDS [64][132] fp32 (with bias).
// Phase 2: quad-group aggregation, add LDS, relu, store (bf16 or fp32).
__global__ __launch_bounds__(256, 2) void gemm_agg_s_k(
    const u16* __restrict__ A, const u16* __restrict__ Wt,
    const float* __restrict__ bias,
    const u16* __restrict__ feat, const int* __restrict__ csr,
    const int* __restrict__ base, const int* __restrict__ cnt,
    void* __restrict__ out, int M, int doRelu, int outF32)
{
  __shared__ float lds[64][132];
  int lane = threadIdx.x & 63;
  int wave = threadIdx.x >> 6;
  int r = lane & 15, q = lane >> 4;
  int row0 = blockIdx.x * 64 + wave * 16;

  // ---- phase 1: C = A@W + bias -> LDS ----
  if (row0 < M) {
    bfrag B[4][8];
#pragma unroll
    for (int k0 = 0; k0 < 4; k0++)
#pragma unroll
      for (int j = 0; j < 8; j++)
        B[k0][j] = *(const bfrag*)(Wt + (size_t)(j * 16 + r) * 128 + k0 * 32 + q * 8);

    int ar = min(row0 + r, M - 1);
    const u16* arow = A + (size_t)ar * 128 + q * 8;
    bfrag a0 = *(const bfrag*)(arow);
    bfrag a1 = *(const bfrag*)(arow + 32);
    bfrag a2 = *(const bfrag*)(arow + 64);
    bfrag a3 = *(const bfrag*)(arow + 96);

    ffrag acc[8];
#pragma unroll
    for (int j = 0; j < 8; j++) acc[j] = (ffrag)0.f;
#pragma unroll
    for (int j = 0; j < 8; j++)
      acc[j] = __builtin_amdgcn_mfma_f32_16x16x32_bf16(B[0][j], a0, acc[j], 0, 0, 0);
#pragma unroll
    for (int j = 0; j < 8; j++)
      acc[j] = __builtin_amdgcn_mfma_f32_16x16x32_bf16(B[1][j], a1, acc[j], 0, 0, 0);
#pragma unroll
    for (int j = 0; j < 8; j++)
      acc[j] = __builtin_amdgcn_mfma_f32_16x16x32_bf16(B[2][j], a2, acc[j], 0, 0, 0);
#pragma unroll
    for (int j = 0; j < 8; j++)
      acc[j] = __builtin_amdgcn_mfma_f32_16x16x32_bf16(B[3][j], a3, acc[j], 0, 0, 0);

#pragma unroll
    for (int j = 0; j < 8; j++) {
      int col0 = j * 16 + q * 4;
      float4 bv = *(const float4*)(bias + col0);
      float4 v = make_float4(acc[j][0] + bv.x, acc[j][1] + bv.y,
                             acc[j][2] + bv.z, acc[j][3] + bv.w);
      *(float4*)&lds[wave * 16 + r][col0] = v;
    }
  }
  __syncthreads();

  // ---- phase 2: aggregation + add + act + store ----
  int g = lane >> 4, lr = lane & 15;
  int lrowbase = wave * 16 + g * 4;
#pragma unroll 1
  for (int t = 0; t < 4; t++) {
    int lrow = lrowbase + t;
    int gv = blockIdx.x * 64 + lrow;
    bool valid = gv < M;
    int b = 0, c = 0;
    if (valid) { b = base[gv]; c = cnt[gv]; }
    float s0=0,s1=0,s2=0,s3=0,s4=0,s5=0,s6=0,s7=0;
    for (int i = 0; i < c; i += 8) {
      int m = c - i;
      int idx[8];
#pragma unroll
      for (int u = 0; u < 8; u++) idx[u] = csr[b + i + min(u, m - 1)];
#pragma unroll
      for (int u = 0; u < 8; u++) {
        uint4 v = ((const uint4*)(feat + (size_t)idx[u] * 128))[lr];
        if (u < m) {
          s0 += bf_lo(v.x); s1 += bf_hi(v.x);
          s2 += bf_lo(v.y); s3 += bf_hi(v.y);
          s4 += bf_lo(v.z); s5 += bf_hi(v.z);
          s6 += bf_lo(v.w); s7 += bf_hi(v.w);
        }
      }
    }
    if (valid) {
      float inv = (c > 0) ? 1.0f / (float)c : 0.0f;
      int col0 = lr * 8;
      float4 d0 = *(const float4*)&lds[lrow][col0];
      float4 d1 = *(const float4*)&lds[lrow][col0 + 4];
      float o0 = s0 * inv + d0.x, o1 = s1 * inv + d0.y;
      float o2 = s2 * inv + d0.z, o3 = s3 * inv + d0.w;
      float o4 = s4 * inv + d1.x, o5 = s5 * inv + d1.y;
      float o6 = s6 * inv + d1.z, o7 = s7 * inv + d1.w;
      if (doRelu) {
        o0 = fmaxf(o0, 0.f); o1 = fmaxf(o1, 0.f);
        o2 = fmaxf(o2, 0.f); o3 = fmaxf(o3, 0.f);
        o4 = fmaxf(o4, 0.f); o5 = fmaxf(o5, 0.f);
        o6 = fmaxf(o6, 0.f); o7 = fmaxf(o7, 0.f);
      }
      if (outF32) {
        float* op = (float*)out + (size_t)gv * 128 + col0;
        *(float4*)op = make_float4(o0, o1, o2, o3);
        *(float4*)(op + 4) = make_float4(o4, o5, o6, o7);
      } else {
        uint4 o;
        o.x = pack2(o0, o1); o.y = pack2(o2, o3);
        o.z = pack2(o4, o5); o.w = pack2(o6, o7);
        ((uint4*)((u16*)out + (size_t)gv * 128))[lr] = o;
      }
    }
  }
}

// ---- B-resident MFMA GEMM (playlist-side) ----------------------------------
__global__ __launch_bounds__(256, 2) void gemm_breg_k(
    const u16* __restrict__ A, const u16* __restrict__ Wt,
    const float* __restrict__ bias, const float* __restrict__ Dadd,
    void* __restrict__ Cout, int M, int doRelu, int outF32)
{
  int lane = threadIdx.x & 63;
  int r = lane & 15, q = lane >> 4;
  int wid = (blockIdx.x * 256 + threadIdx.x) >> 6;
  int nw = gridDim.x * 4;

  bfrag B[4][8];
#pragma unroll
  for (int k0 = 0; k0 < 4; k0++)
#pragma unroll
    for (int j = 0; j < 8; j++)
      B[k0][j] = *(const bfrag*)(Wt + (size_t)(j * 16 + r) * 128 + k0 * 32 + q * 8);

  for (int strip = wid; strip * 16 < M; strip += nw) {
    const u16* arow = A + (size_t)(strip * 16 + r) * 128 + q * 8;
    bfrag a0 = *(const bfrag*)(arow);
    bfrag a1 = *(const bfrag*)(arow + 32);
    bfrag a2 = *(const bfrag*)(arow + 64);
    bfrag a3 = *(const bfrag*)(arow + 96);

    ffrag acc[8];
#pragma unroll
    for (int j = 0; j < 8; j++) acc[j] = (ffrag)0.f;
#pragma unroll
    for (int j = 0; j < 8; j++)
      acc[j] = __builtin_amdgcn_mfma_f32_16x16x32_bf16(B[0][j], a0, acc[j], 0, 0, 0);
#pragma unroll
    for (int j = 0; j < 8; j++)
      acc[j] = __builtin_amdgcn_mfma_f32_16x16x32_bf16(B[1][j], a1, acc[j], 0, 0, 0);
#pragma unroll
    for (int j = 0; j < 8; j++)
      acc[j] = __builtin_amdgcn_mfma_f32_16x16x32_bf16(B[2][j], a2, acc[j], 0, 0, 0);
#pragma unroll
    for (int j = 0; j < 8; j++)
      acc[j] = __builtin_amdgcn_mfma_f32_16x16x32_bf16(B[3][j], a3, acc[j], 0, 0, 0);

    size_t row = (size_t)(strip * 16 + r);
#pragma unroll
    for (int j = 0; j < 8; j++) {
      int col0 = j * 16 + q * 4;
      float v0 = acc[j][0], v1 = acc[j][1], v2 = acc[j][2], v3 = acc[j][3];
      if (bias) {
        float4 bv = *(const float4*)(bias + col0);
        v0 += bv.x; v1 += bv.y; v2 += bv.z; v3 += bv.w;
      }
      if (Dadd) {
        float4 dv = *(const float4*)(Dadd + row * 128 + col0);
        v0 += dv.x; v1 += dv.y; v2 += dv.z; v3 += dv.w;
      }
      if (doRelu) {
        v0 = fmaxf(v0, 0.f); v1 = fmaxf(v1, 0.f);
        v2 = fmaxf(v2, 0.f); v3 = fmaxf(v3, 0.f);
      }
      if (outF32) {
        *(float4*)((float*)Cout + row * 128 + col0) = make_float4(v0, v1, v2, v3);
      } else {
        ushort4 o;
        o.x = f2bf(v0); o.y = f2bf(v1); o.z = f2bf(v2); o.w = f2bf(v3);
        *(ushort4*)((u16*)Cout + row * 128 + col0) = o;
      }
    }
  }
}

// ---------------------------------------------------------------------------

extern "C" void kernel_launch(void* const* d_in, const int* in_sizes, int n_in,
                              void* d_out, int out_size, void* d_ws, size_t ws_size,
                              hipStream_t stream)
{
  const float* song_x = (const float*)d_in[0];
  const int*   pid    = (const int*)d_in[1];
  const int*   e_song = (const int*)d_in[2];
  const int*   e_play = (const int*)d_in[3];
  const float* emb    = (const float*)d_in[4];
  const float* Wl1_sp = (const float*)d_in[5];
  const float* Wr1_sp = (const float*)d_in[6];
  const float* b1_sp  = (const float*)d_in[7];
  const float* Wl1_ps = (const float*)d_in[8];
  const float* Wr1_ps = (const float*)d_in[9];
  const float* b1_ps  = (const float*)d_in[10];
  const float* Wl2_sp = (const float*)d_in[11];
  const float* Wr2_sp = (const float*)d_in[12];
  const float* b2_sp  = (const float*)d_in[13];
  const float* Wl2_ps = (const float*)d_in[14];
  const float* Wr2_ps = (const float*)d_in[15];
  const float* b2_ps  = (const float*)d_in[16];

  const int NS = in_sizes[0] / 128;
  const int NP = in_sizes[1];
  const int E  = in_sizes[2];

  char* w = (char*)d_ws;
  auto alloc = [&](size_t bytes) { char* p = w; w += ws_align(bytes); return p; };
  u16* x_play = (u16*)alloc((size_t)NP * 128 * 2);
  u16* Ms     = (u16*)alloc((size_t)NP * 128 * 2);
  u16* yp     = (u16*)alloc((size_t)NP * 128 * 2);
  u16* p1     = (u16*)alloc((size_t)NP * 128 * 2);
  u16* s1     = (u16*)alloc((size_t)NS * 128 * 2);
  u16* xs     = (u16*)alloc((size_t)NS * 128 * 2);
  float* Gp   = (float*)alloc((size_t)NP * 128 * 4);
  u16* Wt     = (u16*)alloc((size_t)8 * 16384 * 2);  // [mat][n][k]
  int* cnt_p = (int*)alloc(((size_t)NP + NS + 2) * 4);
  int* cnt_s = cnt_p + NP;
  int* gcnt  = cnt_s + NS;
  int* base_p = (int*)alloc((size_t)NP * 4);
  int* cur_p  = (int*)alloc((size_t)NP * 4);
  int* base_s = (int*)alloc((size_t)NS * 4);
  int* cur_s  = (int*)alloc((size_t)NS * 4);
  int* csr_p  = (int*)alloc((size_t)E * 4);
  int* csr_s  = (int*)alloc((size_t)E * 4);

  float* s2_out = (float*)d_out;
  float* p2_out = (float*)d_out + (size_t)NS * 128;

  u16* Wt_l1sp = Wt + 0 * 16384;
  u16* Wt_r1sp = Wt + 1 * 16384;
  u16* Wt_l1ps = Wt + 2 * 16384;
  u16* Wt_r1ps = Wt + 3 * 16384;
  u16* Wt_l2sp = Wt + 4 * 16384;
  u16* Wt_r2sp = Wt + 5 * 16384;
  u16* Wt_l2ps = Wt + 6 * 16384;
  u16* Wt_r2ps = Wt + 7 * 16384;

  const int pch = (NP + 7) / 8, sch = (NS + 7) / 8;
  const int edge_grid = 8 * 104;
  auto ggrid = [](int M) { int s = M / 16; return (s + 7) / 8; };
  const int gP = ggrid(NP);
  const int aggP_b = (NP + 63) / 64;
  const int fusedS_b = (NS + 63) / 64;
  const int nbp = (NP + 255) / 256, nbs = (NS + 255) / 256;

  // ---- prep + CSR build ----
  prep_k<<<1024, 256, 0, stream>>>(Wl1_sp, Wr1_sp, Wl1_ps, Wr1_ps,
                                   Wl2_sp, Wr2_sp, Wl2_ps, Wr2_ps, Wt,
                                   song_x, xs, NS * 32,
                                   emb, pid, x_play, NP,
                                   cnt_p, NP + NS + 2);
  hist_k<<<edge_grid, 256, 0, stream>>>(e_song, e_play, cnt_s, cnt_p, E, pch, sch);
  base2_k<<<nbp + nbs, 256, 0, stream>>>(cnt_p, base_p, cur_p,
                                         cnt_s, base_s, cur_s, gcnt, NP, NS, nbp);
  place_k<<<edge_grid, 256, 0, stream>>>(e_song, e_play, cur_s, cur_p,
                                         csr_s, csr_p, E, pch, sch);

  // ---- layer 1 ----
  // Ms = mean_p(xs)
  agg_quad_k<<<aggP_b, 256, 0, stream>>>(xs, csr_p, base_p, cnt_p, Ms, NP);
  // yp = x_play@Wl1_ps
  gemm_breg_k<<<gP, 256, 0, stream>>>(x_play, Wt_l1ps, nullptr, nullptr,
                                      yp, NP, 0, 0);
  // s1 = relu(mean_s(yp) + xs@Wr1_ps + b1_ps)  [FUSED]
  gemm_agg_s_k<<<fusedS_b, 256, 0, stream>>>(xs, Wt_r1ps, b1_ps,
                                             yp, csr_s, base_s, cnt_s,
                                             s1, NS, 1, 0);
  // Gp = Ms@Wl1_sp (fp32)
  gemm_breg_k<<<gP, 256, 0, stream>>>(Ms, Wt_l1sp, nullptr, nullptr,
                                      (void*)Gp, NP, 0, 1);
  // p1 = relu(x_play@Wr1_sp + b1_sp + Gp)
  gemm_breg_k<<<gP, 256, 0, stream>>>(x_play, Wt_r1sp, b1_sp, Gp,
                                      p1, NP, 1, 0);

  // ---- layer 2 ----
  // Ms = mean_p(s1)
  agg_quad_k<<<aggP_b, 256, 0, stream>>>(s1, csr_p, base_p, cnt_p, Ms, NP);
  // yp = p1@Wl2_ps
  gemm_breg_k<<<gP, 256, 0, stream>>>(p1, Wt_l2ps, nullptr, nullptr,
                                      yp, NP, 0, 0);
  // s2 = mean_s(yp) + s1@Wr2_ps + b2_ps  [FUSED, fp32 out]
  gemm_agg_s_k<<<fusedS_b, 256, 0, stream>>>(s1, Wt_r2ps, b2_ps,
                                             yp, csr_s, base_s, cnt_s,
                                             s2_out, NS, 0, 1);
  // Gp = Ms@Wl2_sp (fp32)
  gemm_breg_k<<<gP, 256, 0, stream>>>(Ms, Wt_l2sp, nullptr, nullptr,
                                      (void*)Gp, NP, 0, 1);
  // p2 = p1@Wr2_sp + b2_sp + Gp (fp32 out)
  gemm_breg_k<<<gP, 256, 0, stream>>>(p1, Wt_r2sp, b2_sp, Gp,
                                      p2_out, NP, 0, 1);
}

// Round 6
// 473.973 us; speedup vs baseline: 1.1756x; 1.1756x over previous
//
#include <hip/hip_runtime.h>

// ---------------------------------------------------------------------------
// 2-layer hetero GraphSAGE, bf16-MFMA.
// R6: - REVERT R5's GEMM+agg fusion (28% occupancy killed it).
//     - Aggregation: one row per 16-lane group (16 rows/block CONCURRENT,
//       no serial row loop), rounds of 8 predicated independent 16B gathers.
//       Fused streaming post-add (+bias'd GEMM result) + relu as in R4.
//     - CSR build XCD-chunked (R4); GEMMs B-resident MFMA (R3).
// ---------------------------------------------------------------------------

typedef __attribute__((ext_vector_type(8))) short bfrag;   // 8 bf16 (4 VGPRs)
typedef __attribute__((ext_vector_type(4))) float ffrag;   // 4 fp32 acc
typedef unsigned short u16;
typedef unsigned int u32;

static inline size_t ws_align(size_t x) { return (x + 255) & ~size_t(255); }

__device__ inline u16 f2bf(float f) {
  union { float f; u32 u; } v; v.f = f;
  u32 r = v.u + 0x7fffu + ((v.u >> 16) & 1u);   // round-nearest-even
  return (u16)(r >> 16);
}
__device__ inline u32 pack2(float a, float b) {
  return (u32)f2bf(a) | ((u32)f2bf(b) << 16);
}
__device__ inline float bf_lo(u32 p) {
  union { u32 u; float f; } v; v.u = p << 16; return v.f;
}
__device__ inline float bf_hi(u32 p) {
  union { u32 u; float f; } v; v.u = p & 0xffff0000u; return v.f;
}

// ---- fused prep: zero counters, conv weights, conv songs, gather playlists -
__global__ __launch_bounds__(256) void prep_k(
    const float* __restrict__ w0, const float* __restrict__ w1,
    const float* __restrict__ w2, const float* __restrict__ w3,
    const float* __restrict__ w4, const float* __restrict__ w5,
    const float* __restrict__ w6, const float* __restrict__ w7,
    u16* __restrict__ Wt,
    const float* __restrict__ song_x, u16* __restrict__ xs, int ns4,
    const float* __restrict__ emb, const int* __restrict__ pid,
    u16* __restrict__ xp, int np,
    int* __restrict__ zero_region, int nzero)
{
  int g0 = blockIdx.x * 256 + threadIdx.x;
  int gs = gridDim.x * 256;
  for (int i = g0; i < nzero; i += gs) zero_region[i] = 0;
  const float* ws[8] = {w0, w1, w2, w3, w4, w5, w6, w7};
  for (int idx = g0; idx < 8 * 16384; idx += gs) {
    int m = idx >> 14, rem = idx & 16383;
    int n = rem >> 7, k = rem & 127;
    Wt[idx] = f2bf(ws[m][k * 128 + n]);
  }
  for (int i = g0; i < ns4; i += gs) {
    float4 v = ((const float4*)song_x)[i];
    ushort4 o;
    o.x = f2bf(v.x); o.y = f2bf(v.y); o.z = f2bf(v.z); o.w = f2bf(v.w);
    ((ushort4*)xs)[i] = o;
  }
  for (int i = g0; i < np * 32; i += gs) {
    int node = i >> 5, q = i & 31;
    float4 v = ((const float4*)(emb + (size_t)pid[node] * 128))[q];
    ushort4 o;
    o.x = f2bf(v.x); o.y = f2bf(v.y); o.z = f2bf(v.z); o.w = f2bf(v.w);
    ((ushort4*)(xp + (size_t)node * 128))[q] = o;
  }
}

// ---- CSR build (XCD-chunked: chunk id = blockIdx&7) ------------------------
__global__ __launch_bounds__(256) void hist_k(
    const int* __restrict__ es, const int* __restrict__ ep,
    int* __restrict__ cnt_s, int* __restrict__ cnt_p,
    int e, int pch, int sch)
{
  int j = blockIdx.x & 7;
  int g = blockIdx.x >> 3;
  int nb = gridDim.x >> 3;
  int p_lo = j * pch, s_lo = j * sch;
  for (int i = g * 256 + threadIdx.x; i < e; i += nb * 256) {
    int p = ep[i], s = es[i];
    if ((u32)(p - p_lo) < (u32)pch) atomicAdd(&cnt_p[p], 1);
    if ((u32)(s - s_lo) < (u32)sch) atomicAdd(&cnt_s[s], 1);
  }
}

__global__ __launch_bounds__(256) void base2_k(
    const int* __restrict__ cnt_p, int* __restrict__ base_p, int* __restrict__ cur_p,
    const int* __restrict__ cnt_s, int* __restrict__ base_s, int* __restrict__ cur_s,
    int* __restrict__ gcnt, int np, int ns, int nbp)
{
  __shared__ int sh[256];
  __shared__ int bb;
  int t = threadIdx.x;
  const int* cnt; int* base; int* cur; int* gc; int n; int i;
  if ((int)blockIdx.x < nbp) {
    cnt = cnt_p; base = base_p; cur = cur_p; gc = gcnt; n = np;
    i = blockIdx.x * 256 + t;
  } else {
    cnt = cnt_s; base = base_s; cur = cur_s; gc = gcnt + 1; n = ns;
    i = (blockIdx.x - nbp) * 256 + t;
  }
  int v = (i < n) ? cnt[i] : 0;
  sh[t] = v;
  __syncthreads();
  for (int off = 1; off < 256; off <<= 1) {
    int tv = (t >= off) ? sh[t - off] : 0;
    __syncthreads();
    sh[t] += tv;
    __syncthreads();
  }
  if (t == 255) bb = atomicAdd(gc, sh[255]);
  __syncthreads();
  if (i < n) {
    int e = bb + sh[t] - v;
    base[i] = e;
    cur[i] = e;
  }
}

__global__ __launch_bounds__(256) void place_k(
    const int* __restrict__ es, const int* __restrict__ ep,
    int* __restrict__ cur_s, int* __restrict__ cur_p,
    int* __restrict__ csr_s, int* __restrict__ csr_p,
    int e, int pch, int sch)
{
  int j = blockIdx.x & 7;
  int g = blockIdx.x >> 3;
  int nb = gridDim.x >> 3;
  int p_lo = j * pch, s_lo = j * sch;
  for (int i = g * 256 + threadIdx.x; i < e; i += nb * 256) {
    int p = ep[i], s = es[i];
    if ((u32)(p - p_lo) < (u32)pch) csr_p[atomicAdd(&cur_p[p], 1)] = s;
    if ((u32)(s - s_lo) < (u32)sch) csr_s[atomicAdd(&cur_s[s], 1)] = p;
  }
}

// ---- quad-group mean aggregation with fused post-add -----------------------
// One 16-lane group per dst row: block 256 = 16 rows concurrently in flight.
// 16 lanes x uint4 (16B) cover the 256B bf16 row. Rounds of 8 predicated
// gathers -> all loads in a round independent (deg~5 song side is
// latency-bound; occupancy stays high: no LDS, ~60 VGPR).
// out[v] = act( mean_{u in csr[v]} feat[u] (+ post[v]) ), post bf16.
__global__ __launch_bounds__(256) void agg_quad_post_k(
    const u16* __restrict__ feat, const int* __restrict__ csr,
    const int* __restrict__ base, const int* __restrict__ cnt,
    const u16* __restrict__ post,
    void* __restrict__ out, int outF32, int doRelu, int n)
{
  int lr = threadIdx.x & 15;
  int grp = threadIdx.x >> 4;           // 0..15
  int gv = blockIdx.x * 16 + grp;
  if (gv >= n) return;
  int b = base[gv], c = cnt[gv];
  float s0=0,s1=0,s2=0,s3=0,s4=0,s5=0,s6=0,s7=0;
  for (int i = 0; i < c; i += 8) {
    int m = c - i;
    int idx[8];
#pragma unroll
    for (int u = 0; u < 8; u++) idx[u] = csr[b + i + min(u, m - 1)];
#pragma unroll
    for (int u = 0; u < 8; u++) {
      uint4 v = ((const uint4*)(feat + (size_t)idx[u] * 128))[lr];
      if (u < m) {
        s0 += bf_lo(v.x); s1 += bf_hi(v.x);
        s2 += bf_lo(v.y); s3 += bf_hi(v.y);
        s4 += bf_lo(v.z); s5 += bf_hi(v.z);
        s6 += bf_lo(v.w); s7 += bf_hi(v.w);
      }
    }
  }
  float inv = (c > 0) ? 1.0f / (float)c : 0.0f;
  s0 *= inv; s1 *= inv; s2 *= inv; s3 *= inv;
  s4 *= inv; s5 *= inv; s6 *= inv; s7 *= inv;
  if (post) {
    uint4 p = ((const uint4*)(post + (size_t)gv * 128))[lr];
    s0 += bf_lo(p.x); s1 += bf_hi(p.x);
    s2 += bf_lo(p.y); s3 += bf_hi(p.y);
    s4 += bf_lo(p.z); s5 += bf_hi(p.z);
    s6 += bf_lo(p.w); s7 += bf_hi(p.w);
  }
  if (doRelu) {
    s0 = fmaxf(s0, 0.f); s1 = fmaxf(s1, 0.f);
    s2 = fmaxf(s2, 0.f); s3 = fmaxf(s3, 0.f);
    s4 = fmaxf(s4, 0.f); s5 = fmaxf(s5, 0.f);
    s6 = fmaxf(s6, 0.f); s7 = fmaxf(s7, 0.f);
  }
  if (outF32) {
    float* op = (float*)out + (size_t)gv * 128 + lr * 8;
    *(float4*)op = make_float4(s0, s1, s2, s3);
    *(float4*)(op + 4) = make_float4(s4, s5, s6, s7);
  } else {
    uint4 o;
    o.x = pack2(s0, s1); o.y = pack2(s2, s3);
    o.z = pack2(s4, s5); o.w = pack2(s6, s7);
    ((uint4*)((u16*)out + (size_t)gv * 128))[lr] = o;
  }
}

// ---- B-resident MFMA GEMM --------------------------------------------------
// C[M,128] = act( A@W (+Dadd_f32) (+bias) ), K=128, Wt = [n][k] bf16.
// Wave holds all of W in registers (32 bfrags = 128 VGPR), grid-strides over
// 16-row strips. Operand-swapped MFMA -> lane holds 4 consecutive cols.
__global__ __launch_bounds__(256, 2) void gemm_breg_k(
    const u16* __restrict__ A, const u16* __restrict__ Wt,
    const float* __restrict__ bias, const float* __restrict__ Dadd,
    void* __restrict__ Cout, int M, int doRelu, int outF32)
{
  int lane = threadIdx.x & 63;
  int r = lane & 15, q = lane >> 4;
  int wid = (blockIdx.x * 256 + threadIdx.x) >> 6;
  int nw = gridDim.x * 4;

  bfrag B[4][8];
#pragma unroll
  for (int k0 = 0; k0 < 4; k0++)
#pragma unroll
    for (int j = 0; j < 8; j++)
      B[k0][j] = *(const bfrag*)(Wt + (size_t)(j * 16 + r) * 128 + k0 * 32 + q * 8);

  for (int strip = wid; strip * 16 < M; strip += nw) {
    const u16* arow = A + (size_t)(strip * 16 + r) * 128 + q * 8;
    bfrag a0 = *(const bfrag*)(arow);
    bfrag a1 = *(const bfrag*)(arow + 32);
    bfrag a2 = *(const bfrag*)(arow + 64);
    bfrag a3 = *(const bfrag*)(arow + 96);

    ffrag acc[8];
#pragma unroll
    for (int j = 0; j < 8; j++) acc[j] = (ffrag)0.f;
#pragma unroll
    for (int j = 0; j < 8; j++)
      acc[j] = __builtin_amdgcn_mfma_f32_16x16x32_bf16(B[0][j], a0, acc[j], 0, 0, 0);
#pragma unroll
    for (int j = 0; j < 8; j++)
      acc[j] = __builtin_amdgcn_mfma_f32_16x16x32_bf16(B[1][j], a1, acc[j], 0, 0, 0);
#pragma unroll
    for (int j = 0; j < 8; j++)
      acc[j] = __builtin_amdgcn_mfma_f32_16x16x32_bf16(B[2][j], a2, acc[j], 0, 0, 0);
#pragma unroll
    for (int j = 0; j < 8; j++)
      acc[j] = __builtin_amdgcn_mfma_f32_16x16x32_bf16(B[3][j], a3, acc[j], 0, 0, 0);

    size_t row = (size_t)(strip * 16 + r);
#pragma unroll
    for (int j = 0; j < 8; j++) {
      int col0 = j * 16 + q * 4;
      float v0 = acc[j][0], v1 = acc[j][1], v2 = acc[j][2], v3 = acc[j][3];
      if (bias) {
        float4 bv = *(const float4*)(bias + col0);
        v0 += bv.x; v1 += bv.y; v2 += bv.z; v3 += bv.w;
      }
      if (Dadd) {
        float4 dv = *(const float4*)(Dadd + row * 128 + col0);
        v0 += dv.x; v1 += dv.y; v2 += dv.z; v3 += dv.w;
      }
      if (doRelu) {
        v0 = fmaxf(v0, 0.f); v1 = fmaxf(v1, 0.f);
        v2 = fmaxf(v2, 0.f); v3 = fmaxf(v3, 0.f);
      }
      if (outF32) {
        *(float4*)((float*)Cout + row * 128 + col0) = make_float4(v0, v1, v2, v3);
      } else {
        ushort4 o;
        o.x = f2bf(v0); o.y = f2bf(v1); o.z = f2bf(v2); o.w = f2bf(v3);
        *(ushort4*)((u16*)Cout + row * 128 + col0) = o;
      }
    }
  }
}

// ---------------------------------------------------------------------------

extern "C" void kernel_launch(void* const* d_in, const int* in_sizes, int n_in,
                              void* d_out, int out_size, void* d_ws, size_t ws_size,
                              hipStream_t stream)
{
  const float* song_x = (const float*)d_in[0];
  const int*   pid    = (const int*)d_in[1];
  const int*   e_song = (const int*)d_in[2];
  const int*   e_play = (const int*)d_in[3];
  const float* emb    = (const float*)d_in[4];
  const float* Wl1_sp = (const float*)d_in[5];
  const float* Wr1_sp = (const float*)d_in[6];
  const float* b1_sp  = (const float*)d_in[7];
  const float* Wl1_ps = (const float*)d_in[8];
  const float* Wr1_ps = (const float*)d_in[9];
  const float* b1_ps  = (const float*)d_in[10];
  const float* Wl2_sp = (const float*)d_in[11];
  const float* Wr2_sp = (const float*)d_in[12];
  const float* b2_sp  = (const float*)d_in[13];
  const float* Wl2_ps = (const float*)d_in[14];
  const float* Wr2_ps = (const float*)d_in[15];
  const float* b2_ps  = (const float*)d_in[16];

  const int NS = in_sizes[0] / 128;
  const int NP = in_sizes[1];
  const int E  = in_sizes[2];

  char* w = (char*)d_ws;
  auto alloc = [&](size_t bytes) { char* p = w; w += ws_align(bytes); return p; };
  u16* x_play = (u16*)alloc((size_t)NP * 128 * 2);
  u16* Ms     = (u16*)alloc((size_t)NP * 128 * 2);
  u16* yp     = (u16*)alloc((size_t)NP * 128 * 2);
  u16* p1     = (u16*)alloc((size_t)NP * 128 * 2);
  u16* s1     = (u16*)alloc((size_t)NS * 128 * 2);
  u16* xs     = (u16*)alloc((size_t)NS * 128 * 2);
  u16* Gs     = (u16*)alloc((size_t)NS * 128 * 2);
  float* Gp   = (float*)alloc((size_t)NP * 128 * 4);
  u16* Wt     = (u16*)alloc((size_t)8 * 16384 * 2);  // [mat][n][k]
  int* cnt_p = (int*)alloc(((size_t)NP + NS + 2) * 4);
  int* cnt_s = cnt_p + NP;
  int* gcnt  = cnt_s + NS;
  int* base_p = (int*)alloc((size_t)NP * 4);
  int* cur_p  = (int*)alloc((size_t)NP * 4);
  int* base_s = (int*)alloc((size_t)NS * 4);
  int* cur_s  = (int*)alloc((size_t)NS * 4);
  int* csr_p  = (int*)alloc((size_t)E * 4);
  int* csr_s  = (int*)alloc((size_t)E * 4);

  float* s2_out = (float*)d_out;
  float* p2_out = (float*)d_out + (size_t)NS * 128;

  u16* Wt_l1sp = Wt + 0 * 16384;
  u16* Wt_r1sp = Wt + 1 * 16384;
  u16* Wt_l1ps = Wt + 2 * 16384;
  u16* Wt_r1ps = Wt + 3 * 16384;
  u16* Wt_l2sp = Wt + 4 * 16384;
  u16* Wt_r2sp = Wt + 5 * 16384;
  u16* Wt_l2ps = Wt + 6 * 16384;
  u16* Wt_r2ps = Wt + 7 * 16384;

  const int pch = (NP + 7) / 8, sch = (NS + 7) / 8;
  const int edge_grid = 8 * 104;
  auto ggrid = [](int M) { int s = M / 16; return (s + 7) / 8; };
  const int gP = ggrid(NP), gS = ggrid(NS);
  const int aggP_b = (NP + 15) / 16, aggS_b = (NS + 15) / 16;
  const int nbp = (NP + 255) / 256, nbs = (NS + 255) / 256;

  // ---- prep + CSR build ----
  prep_k<<<1024, 256, 0, stream>>>(Wl1_sp, Wr1_sp, Wl1_ps, Wr1_ps,
                                   Wl2_sp, Wr2_sp, Wl2_ps, Wr2_ps, Wt,
                                   song_x, xs, NS * 32,
                                   emb, pid, x_play, NP,
                                   cnt_p, NP + NS + 2);
  hist_k<<<edge_grid, 256, 0, stream>>>(e_song, e_play, cnt_s, cnt_p, E, pch, sch);
  base2_k<<<nbp + nbs, 256, 0, stream>>>(cnt_p, base_p, cur_p,
                                         cnt_s, base_s, cur_s, gcnt, NP, NS, nbp);
  place_k<<<edge_grid, 256, 0, stream>>>(e_song, e_play, cur_s, cur_p,
                                         csr_s, csr_p, E, pch, sch);

  // ---- layer 1 ----
  // Ms = mean_p(xs)
  agg_quad_post_k<<<aggP_b, 256, 0, stream>>>(xs, csr_p, base_p, cnt_p,
                                              nullptr, Ms, 0, 0, NP);
  // yp = x_play@Wl1_ps
  gemm_breg_k<<<gP, 256, 0, stream>>>(x_play, Wt_l1ps, nullptr, nullptr,
                                      yp, NP, 0, 0);
  // Gs = xs@Wr1_ps + b1_ps (bf16)
  gemm_breg_k<<<gS, 256, 0, stream>>>(xs, Wt_r1ps, b1_ps, nullptr,
                                      (void*)Gs, NS, 0, 0);
  // s1 = relu(mean_s(yp) + Gs)
  agg_quad_post_k<<<aggS_b, 256, 0, stream>>>(yp, csr_s, base_s, cnt_s,
                                              Gs, s1, 0, 1, NS);
  // Gp = Ms@Wl1_sp (fp32)
  gemm_breg_k<<<gP, 256, 0, stream>>>(Ms, Wt_l1sp, nullptr, nullptr,
                                      (void*)Gp, NP, 0, 1);
  // p1 = relu(x_play@Wr1_sp + b1_sp + Gp)
  gemm_breg_k<<<gP, 256, 0, stream>>>(x_play, Wt_r1sp, b1_sp, Gp,
                                      p1, NP, 1, 0);

  // ---- layer 2 ----
  // Ms = mean_p(s1)
  agg_quad_post_k<<<aggP_b, 256, 0, stream>>>(s1, csr_p, base_p, cnt_p,
                                              nullptr, Ms, 0, 0, NP);
  // yp = p1@Wl2_ps
  gemm_breg_k<<<gP, 256, 0, stream>>>(p1, Wt_l2ps, nullptr, nullptr,
                                      yp, NP, 0, 0);
  // Gs = s1@Wr2_ps + b2_ps (bf16)
  gemm_breg_k<<<gS, 256, 0, stream>>>(s1, Wt_r2ps, b2_ps, nullptr,
                                      (void*)Gs, NS, 0, 0);
  // s2 = mean_s(yp) + Gs  (fp32 out)
  agg_quad_post_k<<<aggS_b, 256, 0, stream>>>(yp, csr_s, base_s, cnt_s,
                                              Gs, s2_out, 1, 0, NS);
  // Gp = Ms@Wl2_sp (fp32)
  gemm_breg_k<<<gP, 256, 0, stream>>>(Ms, Wt_l2sp, nullptr, nullptr,
                                      (void*)Gp, NP, 0, 1);
  // p2 = p1@Wr2_sp + b2_sp + Gp (fp32 out)
  gemm_breg_k<<<gP, 256, 0, stream>>>(p1, Wt_r2sp, b2_sp, Gp,
                                      p2_out, NP, 0, 1);
}